// Round 25
// baseline (226.892 us; speedup 1.0000x reference)
//
#include <hip/hip_runtime.h>
#include <math.h>

#define N_NODES 40000
#define N_EDGES 640000
#define IN_DIM 128
#define EDGE_DIM 64
#define HID 128

typedef __attribute__((ext_vector_type(8))) short bf16x8;
typedef __attribute__((ext_vector_type(4))) float f32x4;

__device__ __forceinline__ ushort f2bf(float f) {
    unsigned int x = __float_as_uint(f);
    x += 0x7fffu + ((x >> 16) & 1u);
    return (ushort)(x >> 16);
}
__device__ __forceinline__ float bf2f(ushort u) {
    return __uint_as_float(((unsigned int)u) << 16);
}
// tanh(x) = 1 - 2/(e^{2x}+1); e^{2x}=inf -> 1, e^{2x}=0 -> -1 (no NaN)
__device__ __forceinline__ float tanh_fast(float x) {
    return 1.f - __fdividef(2.f, __expf(2.f * x) + 1.f);
}

// ---------------------------------------------------------------------------
// Launch A (256 thr): blocks 0..32 = wcomb ; blocks 33..2532 = hist
// ---------------------------------------------------------------------------
__global__ __launch_bounds__(256) void k_A(
    const float* __restrict__ W_edge, const float* __restrict__ W1,
    const float* __restrict__ b_att1, const float* __restrict__ b_edge,
    float* __restrict__ Wc, float* __restrict__ b_eff,
    const int* __restrict__ srcI, int* __restrict__ cnt)
{
    const int bid = blockIdx.x;
    if (bid < 33) {
        const float* W1he = W1 + 256 * 128;
        if (bid == 32) {
            const int n = threadIdx.x;
            if (n < 128) {
                float s = b_att1[n];
                for (int k = 0; k < 128; ++k) s = fmaf(b_edge[k], W1he[k * 128 + n], s);
                b_eff[n] = s;
            }
            return;
        }
        const int idx = bid * 256 + threadIdx.x;
        const int row = idx >> 7, n = idx & 127;
        float s = 0.f;
        for (int k = 0; k < 128; ++k) s = fmaf(W_edge[row * 128 + k], W1he[k * 128 + n], s);
        Wc[idx] = s;
    } else {
        const int e = (bid - 33) * 256 + threadIdx.x;
        atomicAdd(&cnt[srcI[e]], 1);
    }
}

// ---------------------------------------------------------------------------
// Launch B (1024 thr): blocks 0..71 = pack ; block 72 = scan
// ---------------------------------------------------------------------------
__global__ __launch_bounds__(1024) void k_B(
    const float* __restrict__ W1, const float* __restrict__ Wc,
    const float* __restrict__ Wn, const float* __restrict__ Wo,
    ushort* __restrict__ packB, ushort* __restrict__ packA,
    ushort* __restrict__ packN, ushort* __restrict__ packO,
    const int* __restrict__ cnt, int* __restrict__ rowptr)
{
    const int bid = blockIdx.x;
    if (bid < 72) {
        const int idx = bid * 1024 + threadIdx.x;   // 0..73727
        if (idx < 32768) {
            const int j = idx & 7, lane = (idx >> 3) & 63, nt = (idx >> 9) & 7, k0 = idx >> 12;
            const int k = k0 * 32 + (lane >> 4) * 8 + j;
            const int n = nt * 16 + (lane & 15);
            packB[idx] = f2bf(W1[k * 128 + n]);
        } else if (idx < 40960) {
            const int i2 = idx - 32768;
            const int j = i2 & 7, lane = (i2 >> 3) & 63, mt = (i2 >> 9) & 7, k0 = i2 >> 12;
            const int k = k0 * 32 + (lane >> 4) * 8 + j;
            const int row = mt * 16 + (lane & 15);
            packA[i2] = f2bf(Wc[k * 128 + row]);
        } else if (idx < 57344) {
            const int i3 = idx - 40960;
            const int j = i3 & 7, lane = (i3 >> 3) & 63, nt = (i3 >> 9) & 7, k0 = i3 >> 12;
            const int k = k0 * 32 + (lane >> 4) * 8 + j;
            const int n = nt * 16 + (lane & 15);
            packN[i3] = f2bf(Wn[k * 128 + n]);
        } else {
            const int i4 = idx - 57344;
            const int j = i4 & 7, lane = (i4 >> 3) & 63, nt = (i4 >> 9) & 7, k0 = i4 >> 12;
            const int k = k0 * 32 + (lane >> 4) * 8 + j;
            const int n = nt * 16 + (lane & 15);
            packO[i4] = f2bf(Wo[k * 128 + n]);
        }
        return;
    }
    // --- scan (single block, 4 elems/thread) ---
    __shared__ int wsum[16];
    __shared__ int carry;
    const int tid = threadIdx.x, lane = tid & 63, wid = tid >> 6;
    if (tid == 0) { carry = 0; rowptr[0] = 0; }
    __syncthreads();
    for (int base = 0; base < N_NODES; base += 4096) {
        const int i = base + tid * 4;
        int4 c = {0, 0, 0, 0};
        if (i < N_NODES) c = *reinterpret_cast<const int4*>(cnt + i);
        const int tsum = c.x + c.y + c.z + c.w;
        int v = tsum;
#pragma unroll
        for (int d = 1; d < 64; d <<= 1) {
            const int t = __shfl_up(v, d, 64);
            if (lane >= d) v += t;
        }
        if (lane == 63) wsum[wid] = v;
        __syncthreads();
        if (wid == 0 && lane < 16) {
            int w = wsum[lane];
#pragma unroll
            for (int d = 1; d < 16; d <<= 1) {
                const int t = __shfl_up(w, d, 16);
                if ((lane & 15) >= d) w += t;
            }
            wsum[lane] = w;
        }
        __syncthreads();
        const int off = (wid == 0) ? 0 : wsum[wid - 1];
        const int excl = carry + off + v - tsum;
        if (i < N_NODES) {
            rowptr[i + 1] = excl + c.x;
            rowptr[i + 2] = excl + c.x + c.y;
            rowptr[i + 3] = excl + c.x + c.y + c.z;
            rowptr[i + 4] = excl + tsum;
        }
        const int total = wsum[15];
        __syncthreads();
        if (tid == 0) carry += total;
        __syncthreads();
    }
}

// ---------------------------------------------------------------------------
// Launch C (256 thr): blocks 0..624 = node_hg3 ; blocks 625..3124 = fill.
// ---------------------------------------------------------------------------
__global__ __launch_bounds__(256) void k_C(
    const float* __restrict__ X, const ushort* __restrict__ packN,
    const ushort* __restrict__ packB, const ushort* __restrict__ packO,
    const float* __restrict__ b, const float* __restrict__ b_eff,
    ushort* __restrict__ G1, ushort* __restrict__ G2, ushort* __restrict__ G3,
    const int* __restrict__ srcI, const int* __restrict__ dstI,
    const int* __restrict__ rowptr, int* __restrict__ cursor,
    int2* __restrict__ edrec)
{
    const int bid = blockIdx.x;
    if (bid >= 625) {
        const int e = (bid - 625) * 256 + threadIdx.x;
        const int s = srcI[e];
        const int pos = rowptr[s] + atomicAdd(&cursor[s], 1);
        int2 rec;
        rec.x = e;
        rec.y = (s << 16) | dstI[e];
        edrec[pos] = rec;
        return;
    }
    __shared__ ushort hs[4][16][144];   // 18 KB
    const int tid = threadIdx.x;
    const int wave = tid >> 6, lane = tid & 63;
    const int r = lane & 15, g = lane >> 4;
    const int nbase = bid * 64 + wave * 16;
    const float* rowX = X + (size_t)(nbase + r) * 128 + g * 8;
    const bf16x8* BpN = reinterpret_cast<const bf16x8*>(packN);
    const bf16x8* BpB = reinterpret_cast<const bf16x8*>(packB);
    const bf16x8* BpO = reinterpret_cast<const bf16x8*>(packO);

    f32x4 acc[8];
#pragma unroll
    for (int nt = 0; nt < 8; ++nt) {
        const float bv = b[nt * 16 + r];
        acc[nt] = (f32x4){bv, bv, bv, bv};
    }
#pragma unroll
    for (int k0 = 0; k0 < 4; ++k0) {
        const float4 u0 = *reinterpret_cast<const float4*>(rowX + k0 * 32);
        const float4 u1 = *reinterpret_cast<const float4*>(rowX + k0 * 32 + 4);
        bf16x8 a;
        a[0] = (short)f2bf(u0.x); a[1] = (short)f2bf(u0.y);
        a[2] = (short)f2bf(u0.z); a[3] = (short)f2bf(u0.w);
        a[4] = (short)f2bf(u1.x); a[5] = (short)f2bf(u1.y);
        a[6] = (short)f2bf(u1.z); a[7] = (short)f2bf(u1.w);
#pragma unroll
        for (int nt = 0; nt < 8; ++nt)
            acc[nt] = __builtin_amdgcn_mfma_f32_16x16x32_bf16(
                a, BpN[(k0 * 8 + nt) * 64 + lane], acc[nt], 0, 0, 0);
    }
#pragma unroll
    for (int nt = 0; nt < 8; ++nt) {
#pragma unroll
        for (int q = 0; q < 4; ++q)
            hs[wave][g * 4 + q][nt * 16 + r] = f2bf(acc[nt][q]);
    }

    bf16x8 afr[4];
#pragma unroll
    for (int k0 = 0; k0 < 4; ++k0)
        afr[k0] = *reinterpret_cast<const bf16x8*>(&hs[wave][r][k0 * 32 + g * 8]);

    const int coff = (r >> 2) * 32 + (r & 3);

    // G1 = h @ W1a + b_eff (permuted store)
#pragma unroll
    for (int nt = 0; nt < 8; ++nt) acc[nt] = (f32x4){0.f, 0.f, 0.f, 0.f};
#pragma unroll
    for (int k0 = 0; k0 < 4; ++k0) {
#pragma unroll
        for (int nt = 0; nt < 8; ++nt)
            acc[nt] = __builtin_amdgcn_mfma_f32_16x16x32_bf16(
                afr[k0], BpB[(k0 * 8 + nt) * 64 + lane], acc[nt], 0, 0, 0);
    }
#pragma unroll
    for (int nt = 0; nt < 8; ++nt) {
        const float bv = b_eff[nt * 16 + r];
#pragma unroll
        for (int q = 0; q < 4; ++q)
            G1[(size_t)(nbase + g * 4 + q) * 128 + coff + nt * 4] = f2bf(acc[nt][q] + bv);
    }

    // G2 = h @ W1b (permuted store)
#pragma unroll
    for (int nt = 0; nt < 8; ++nt) acc[nt] = (f32x4){0.f, 0.f, 0.f, 0.f};
#pragma unroll
    for (int k0 = 0; k0 < 4; ++k0) {
#pragma unroll
        for (int nt = 0; nt < 8; ++nt)
            acc[nt] = __builtin_amdgcn_mfma_f32_16x16x32_bf16(
                afr[k0], BpB[((k0 + 4) * 8 + nt) * 64 + lane], acc[nt], 0, 0, 0);
    }
#pragma unroll
    for (int nt = 0; nt < 8; ++nt) {
#pragma unroll
        for (int q = 0; q < 4; ++q)
            G2[(size_t)(nbase + g * 4 + q) * 128 + coff + nt * 4] = f2bf(acc[nt][q]);
    }

    // G3 = h @ W_out (row-major store)
#pragma unroll
    for (int nt = 0; nt < 8; ++nt) acc[nt] = (f32x4){0.f, 0.f, 0.f, 0.f};
#pragma unroll
    for (int k0 = 0; k0 < 4; ++k0) {
#pragma unroll
        for (int nt = 0; nt < 8; ++nt)
            acc[nt] = __builtin_amdgcn_mfma_f32_16x16x32_bf16(
                afr[k0], BpO[(k0 * 8 + nt) * 64 + lane], acc[nt], 0, 0, 0);
    }
#pragma unroll
    for (int nt = 0; nt < 8; ++nt) {
#pragma unroll
        for (int q = 0; q < 4; ++q)
            G3[(size_t)(nbase + g * 4 + q) * 128 + nt * 16 + r] = f2bf(acc[nt][q]);
    }
}

// ---------------------------------------------------------------------------
// K2 v11: CSR-ordered edge attention, 2-tile software pipeline per wave.
// Wave handles 32 CSR slots (two 16-edge tiles). All long-latency loads
// (edrec, EF floats, G2) for BOTH tiles are issued up front; tile1's EF
// granules stay in flight under tile0's MFMA+tanh (~600 cyc), doubling
// per-wave memory parallelism on the random 256B EF reads.
// ---------------------------------------------------------------------------
__global__ __launch_bounds__(256) void k_edge_att_v11(
    const int2* __restrict__ edrec, const float* __restrict__ EF,
    const ushort* __restrict__ G1, const ushort* __restrict__ G2,
    const ushort* __restrict__ packA,
    const float* __restrict__ W2, const float* __restrict__ b2,
    float* __restrict__ csr_p)
{
    const int tid = threadIdx.x;
    const int wave = tid >> 6, lane = tid & 63;
    const int r = lane & 15, g = lane >> 4;
    const int pbase = blockIdx.x * 128 + wave * 32;
    const int pos0 = pbase + r, pos1 = pbase + 16 + r;

    const int2 rec0 = edrec[pos0];
    const int2 rec1 = edrec[pos1];
    const int e0 = rec0.x, di0 = rec0.y & 0xffff, si0 = ((unsigned)rec0.y) >> 16;
    const int e1 = rec1.x, di1 = rec1.y & 0xffff, si1 = ((unsigned)rec1.y) >> 16;

    // ---- issue ALL long-latency loads up front ----
    const float* rowE0 = EF + (size_t)e0 * 64 + g * 8;
    const float* rowE1 = EF + (size_t)e1 * 64 + g * 8;
    const float4 u0a = *reinterpret_cast<const float4*>(rowE0);
    const float4 u0b = *reinterpret_cast<const float4*>(rowE0 + 4);
    const float4 v0a = *reinterpret_cast<const float4*>(rowE0 + 32);
    const float4 v0b = *reinterpret_cast<const float4*>(rowE0 + 36);
    const float4 u1a = *reinterpret_cast<const float4*>(rowE1);
    const float4 u1b = *reinterpret_cast<const float4*>(rowE1 + 4);
    const float4 v1a = *reinterpret_cast<const float4*>(rowE1 + 32);
    const float4 v1b = *reinterpret_cast<const float4*>(rowE1 + 36);

    const ushort* g2base0 = G2 + (size_t)di0 * 128 + g * 32;
    const ushort* g2base1 = G2 + (size_t)di1 * 128 + g * 32;
    bf16x8 g2r0[4], g2r1[4];
#pragma unroll
    for (int m2 = 0; m2 < 4; ++m2) {
        g2r0[m2] = *reinterpret_cast<const bf16x8*>(g2base0 + m2 * 8);
        g2r1[m2] = *reinterpret_cast<const bf16x8*>(g2base1 + m2 * 8);
    }

    const bf16x8* Ap = reinterpret_cast<const bf16x8*>(packA);  // 16 KB, L2-hot
    const float bb2 = b2[0];

    // ================= tile 0 =================
    {
        const ushort* g1base = G1 + (size_t)si0 * 128 + g * 32;
        f32x4 acc[8];
#pragma unroll
        for (int m2 = 0; m2 < 4; ++m2) {
            const bf16x8 a = *reinterpret_cast<const bf16x8*>(g1base + m2 * 8);
#pragma unroll
            for (int q = 0; q < 4; ++q) {
                acc[2 * m2][q]     = bf2f((ushort)a[q]);
                acc[2 * m2 + 1][q] = bf2f((ushort)a[4 + q]);
            }
        }
        bf16x8 b0, b1;
        b0[0] = (short)f2bf(u0a.x); b0[1] = (short)f2bf(u0a.y);
        b0[2] = (short)f2bf(u0a.z); b0[3] = (short)f2bf(u0a.w);
        b0[4] = (short)f2bf(u0b.x); b0[5] = (short)f2bf(u0b.y);
        b0[6] = (short)f2bf(u0b.z); b0[7] = (short)f2bf(u0b.w);
        b1[0] = (short)f2bf(v0a.x); b1[1] = (short)f2bf(v0a.y);
        b1[2] = (short)f2bf(v0a.z); b1[3] = (short)f2bf(v0a.w);
        b1[4] = (short)f2bf(v0b.x); b1[5] = (short)f2bf(v0b.y);
        b1[6] = (short)f2bf(v0b.z); b1[7] = (short)f2bf(v0b.w);
#pragma unroll
        for (int mt = 0; mt < 8; ++mt)
            acc[mt] = __builtin_amdgcn_mfma_f32_16x16x32_bf16(
                Ap[(0 * 8 + mt) * 64 + lane], b0, acc[mt], 0, 0, 0);
#pragma unroll
        for (int mt = 0; mt < 8; ++mt)
            acc[mt] = __builtin_amdgcn_mfma_f32_16x16x32_bf16(
                Ap[(1 * 8 + mt) * 64 + lane], b1, acc[mt], 0, 0, 0);

        float part = 0.f;
#pragma unroll
        for (int mt = 0; mt < 8; ++mt) {
            const bf16x8 gr = g2r0[mt >> 1];
            const int h4 = (mt & 1) * 4;
            const float4 w2v = *reinterpret_cast<const float4*>(W2 + mt * 16 + g * 4);
            const float z0 = acc[mt][0] + bf2f((ushort)gr[h4 + 0]);
            const float z1 = acc[mt][1] + bf2f((ushort)gr[h4 + 1]);
            const float z2 = acc[mt][2] + bf2f((ushort)gr[h4 + 2]);
            const float z3 = acc[mt][3] + bf2f((ushort)gr[h4 + 3]);
            part = fmaf(tanh_fast(z0), w2v.x, part);
            part = fmaf(tanh_fast(z1), w2v.y, part);
            part = fmaf(tanh_fast(z2), w2v.z, part);
            part = fmaf(tanh_fast(z3), w2v.w, part);
        }
        part += __shfl_xor(part, 16, 64);
        part += __shfl_xor(part, 32, 64);
        if (lane < 16) csr_p[pos0] = __expf(part + bb2);
    }

    // ================= tile 1 =================
    {
        const ushort* g1base = G1 + (size_t)si1 * 128 + g * 32;
        f32x4 acc[8];
#pragma unroll
        for (int m2 = 0; m2 < 4; ++m2) {
            const bf16x8 a = *reinterpret_cast<const bf16x8*>(g1base + m2 * 8);
#pragma unroll
            for (int q = 0; q < 4; ++q) {
                acc[2 * m2][q]     = bf2f((ushort)a[q]);
                acc[2 * m2 + 1][q] = bf2f((ushort)a[4 + q]);
            }
        }
        bf16x8 b0, b1;
        b0[0] = (short)f2bf(u1a.x); b0[1] = (short)f2bf(u1a.y);
        b0[2] = (short)f2bf(u1a.z); b0[3] = (short)f2bf(u1a.w);
        b0[4] = (short)f2bf(u1b.x); b0[5] = (short)f2bf(u1b.y);
        b0[6] = (short)f2bf(u1b.z); b0[7] = (short)f2bf(u1b.w);
        b1[0] = (short)f2bf(v1a.x); b1[1] = (short)f2bf(v1a.y);
        b1[2] = (short)f2bf(v1a.z); b1[3] = (short)f2bf(v1a.w);
        b1[4] = (short)f2bf(v1b.x); b1[5] = (short)f2bf(v1b.y);
        b1[6] = (short)f2bf(v1b.z); b1[7] = (short)f2bf(v1b.w);
#pragma unroll
        for (int mt = 0; mt < 8; ++mt)
            acc[mt] = __builtin_amdgcn_mfma_f32_16x16x32_bf16(
                Ap[(0 * 8 + mt) * 64 + lane], b0, acc[mt], 0, 0, 0);
#pragma unroll
        for (int mt = 0; mt < 8; ++mt)
            acc[mt] = __builtin_amdgcn_mfma_f32_16x16x32_bf16(
                Ap[(1 * 8 + mt) * 64 + lane], b1, acc[mt], 0, 0, 0);

        float part = 0.f;
#pragma unroll
        for (int mt = 0; mt < 8; ++mt) {
            const bf16x8 gr = g2r1[mt >> 1];
            const int h4 = (mt & 1) * 4;
            const float4 w2v = *reinterpret_cast<const float4*>(W2 + mt * 16 + g * 4);
            const float z0 = acc[mt][0] + bf2f((ushort)gr[h4 + 0]);
            const float z1 = acc[mt][1] + bf2f((ushort)gr[h4 + 1]);
            const float z2 = acc[mt][2] + bf2f((ushort)gr[h4 + 2]);
            const float z3 = acc[mt][3] + bf2f((ushort)gr[h4 + 3]);
            part = fmaf(tanh_fast(z0), w2v.x, part);
            part = fmaf(tanh_fast(z1), w2v.y, part);
            part = fmaf(tanh_fast(z2), w2v.z, part);
            part = fmaf(tanh_fast(z3), w2v.w, part);
        }
        part += __shfl_xor(part, 16, 64);
        part += __shfl_xor(part, 32, 64);
        if (lane < 16) csr_p[pos1] = __expf(part + bb2);
    }
}

// ---------------------------------------------------------------------------
// K3: per-node gather-aggregate over G3 + fused bias + LayerNorm + ReLU.
// ---------------------------------------------------------------------------
__global__ __launch_bounds__(256) void k_agg(
    const int* __restrict__ rowptr, const float* __restrict__ csr_p,
    const int2* __restrict__ edrec, const ushort* __restrict__ G3,
    const float* __restrict__ b_out, const float* __restrict__ gamma,
    const float* __restrict__ beta, float* __restrict__ OUT)
{
    const int tid = threadIdx.x;
    const int wave = tid >> 6, lane = tid & 63;
    const int slot = lane >> 4, tc = lane & 15;
    const int n = blockIdx.x * 4 + wave;
    const int beg = rowptr[n], end = rowptr[n + 1];

    float v[8];
#pragma unroll
    for (int i = 0; i < 8; ++i) v[i] = 0.f;
    float sp = 0.f;

    int j = beg + slot;
    for (; j + 4 < end; j += 8) {
        const float p0 = csr_p[j];
        const int d0 = edrec[j].y & 0xffff;
        const float p1 = csr_p[j + 4];
        const int d1 = edrec[j + 4].y & 0xffff;
        const bf16x8 h0 = *reinterpret_cast<const bf16x8*>(G3 + (size_t)d0 * 128 + tc * 8);
        const bf16x8 h1 = *reinterpret_cast<const bf16x8*>(G3 + (size_t)d1 * 128 + tc * 8);
#pragma unroll
        for (int i = 0; i < 8; ++i) {
            v[i] = fmaf(p0, bf2f((ushort)h0[i]), v[i]);
            v[i] = fmaf(p1, bf2f((ushort)h1[i]), v[i]);
        }
        sp += p0 + p1;
    }
    for (; j < end; j += 4) {
        const float p = csr_p[j];
        const int d = edrec[j].y & 0xffff;
        const bf16x8 hv = *reinterpret_cast<const bf16x8*>(G3 + (size_t)d * 128 + tc * 8);
#pragma unroll
        for (int i = 0; i < 8; ++i) v[i] = fmaf(p, bf2f((ushort)hv[i]), v[i]);
        sp += p;
    }
#pragma unroll
    for (int m = 16; m <= 32; m <<= 1) {
#pragma unroll
        for (int i = 0; i < 8; ++i) v[i] += __shfl_xor(v[i], m, 64);
        sp += __shfl_xor(sp, m, 64);
    }

    const float inv = (end > beg) ? 1.f / sp : 0.f;
    const float4 bo0 = *reinterpret_cast<const float4*>(b_out + tc * 8);
    const float4 bo1 = *reinterpret_cast<const float4*>(b_out + tc * 8 + 4);
    float x[8];
    x[0] = fmaf(v[0], inv, bo0.x); x[1] = fmaf(v[1], inv, bo0.y);
    x[2] = fmaf(v[2], inv, bo0.z); x[3] = fmaf(v[3], inv, bo0.w);
    x[4] = fmaf(v[4], inv, bo1.x); x[5] = fmaf(v[5], inv, bo1.y);
    x[6] = fmaf(v[6], inv, bo1.z); x[7] = fmaf(v[7], inv, bo1.w);

    float s1 = 0.f, s2 = 0.f;
#pragma unroll
    for (int i = 0; i < 8; ++i) { s1 += x[i]; s2 = fmaf(x[i], x[i], s2); }
#pragma unroll
    for (int m = 1; m <= 8; m <<= 1) {
        s1 += __shfl_xor(s1, m, 64);
        s2 += __shfl_xor(s2, m, 64);
    }
    const float mu = s1 * (1.f / 128.f);
    const float var = s2 * (1.f / 128.f) - mu * mu;
    const float rr = rsqrtf(var + 1e-5f);

    if (lane < 16) {
        const float4 ga0 = *reinterpret_cast<const float4*>(gamma + tc * 8);
        const float4 ga1 = *reinterpret_cast<const float4*>(gamma + tc * 8 + 4);
        const float4 be0 = *reinterpret_cast<const float4*>(beta + tc * 8);
        const float4 be1 = *reinterpret_cast<const float4*>(beta + tc * 8 + 4);
        float4 o0, o1;
        o0.x = (x[0] - mu) * rr * ga0.x + be0.x;
        o0.y = (x[1] - mu) * rr * ga0.y + be0.y;
        o0.z = (x[2] - mu) * rr * ga0.z + be0.z;
        o0.w = (x[3] - mu) * rr * ga0.w + be0.w;
        o1.x = (x[4] - mu) * rr * ga1.x + be1.x;
        o1.y = (x[5] - mu) * rr * ga1.y + be1.y;
        o1.z = (x[6] - mu) * rr * ga1.z + be1.z;
        o1.w = (x[7] - mu) * rr * ga1.w + be1.w;
        o0.x = o0.x > 0.f ? o0.x : 0.f; o0.y = o0.y > 0.f ? o0.y : 0.f;
        o0.z = o0.z > 0.f ? o0.z : 0.f; o0.w = o0.w > 0.f ? o0.w : 0.f;
        o1.x = o1.x > 0.f ? o1.x : 0.f; o1.y = o1.y > 0.f ? o1.y : 0.f;
        o1.z = o1.z > 0.f ? o1.z : 0.f; o1.w = o1.w > 0.f ? o1.w : 0.f;
        float* orow = OUT + (size_t)n * 128 + tc * 8;
        *reinterpret_cast<float4*>(orow) = o0;
        *reinterpret_cast<float4*>(orow + 4) = o1;
    }
}

// ---------------------------------------------------------------------------
extern "C" void kernel_launch(void* const* d_in, const int* in_sizes, int n_in,
                              void* d_out, int out_size, void* d_ws, size_t ws_size,
                              hipStream_t stream)
{
    const float* node_features = (const float*)d_in[0];
    const int*   edge_index    = (const int*)d_in[1];
    const float* edge_features = (const float*)d_in[2];
    const float* W_node  = (const float*)d_in[3];
    const float* b_node  = (const float*)d_in[4];
    const float* W_edge  = (const float*)d_in[5];
    const float* b_edge  = (const float*)d_in[6];
    const float* W_att1  = (const float*)d_in[7];
    const float* b_att1  = (const float*)d_in[8];
    const float* W_att2  = (const float*)d_in[9];
    const float* b_att2  = (const float*)d_in[10];
    const float* W_out   = (const float*)d_in[11];
    const float* b_out   = (const float*)d_in[12];
    const float* ln_gamma = (const float*)d_in[13];
    const float* ln_beta  = (const float*)d_in[14];
    float* out = (float*)d_out;

    // workspace layout (byte offsets, 16B-aligned)
    char* ws = (char*)d_ws;
    ushort* G3      = (ushort*)(ws);                   // 10,240,000 B
    ushort* G1      = (ushort*)(ws + 10240000);        // 10,240,000 B
    ushort* G2      = (ushort*)(ws + 20480000);        // 10,240,000 B
    float*  csr_p   = (float*)(ws + 40960000);         //  2,560,000 B
    int2*   edrec   = (int2*)(ws + 43520000);          //  5,120,000 B
    int*    rowptr  = (int*)(ws + 48640000);           //    160,004 B
    int*    cnt     = (int*)(ws + 48800016);           //    160,000 B
    int*    cursor  = (int*)(ws + 48960016);           //    160,000 B (contiguous after cnt)
    float*  Wc      = (float*)(ws + 49120016);         //     32,768 B
    float*  b_eff   = (float*)(ws + 49152784);         //        512 B
    ushort* packB   = (ushort*)(ws + 49153296);        //     65,536 B
    ushort* packA   = (ushort*)(ws + 49218832);        //     16,384 B
    ushort* packN   = (ushort*)(ws + 49235216);        //     32,768 B
    ushort* packO   = (ushort*)(ws + 49267984);        //     32,768 B

    const int* srcI = edge_index;
    const int* dstI = edge_index + N_EDGES;

    // zero histogram + fill cursors (contiguous)
    hipMemsetAsync(cnt, 0, 320000, stream);

    // A: wcomb (33) + hist (2500)
    k_A<<<2533, 256, 0, stream>>>(W_edge, W_att1, b_att1, b_edge, Wc, b_eff,
                                  srcI, cnt);
    // B: pack (72x1024) + scan (1)
    k_B<<<73, 1024, 0, stream>>>(W_att1, Wc, W_node, W_out,
                                 packB, packA, packN, packO, cnt, rowptr);
    // C: node_hg3 (625) + fill (2500)
    k_C<<<3125, 256, 0, stream>>>(node_features, packN, packB, packO,
                                  b_node, b_eff, G1, G2, G3,
                                  srcI, dstI, rowptr, cursor, edrec);
    k_edge_att_v11<<<N_EDGES / 128, 256, 0, stream>>>(edrec, edge_features,
                                                      G1, G2, packA, W_att2, b_att2,
                                                      csr_p);
    k_agg<<<N_NODES / 4, 256, 0, stream>>>(rowptr, csr_p, edrec, G3,
                                           b_out, ln_gamma, ln_beta, out);
}

// Round 26
// 210.890 us; speedup vs baseline: 1.0759x; 1.0759x over previous
//
#include <hip/hip_runtime.h>
#include <math.h>

#define N_NODES 40000
#define N_EDGES 640000
#define IN_DIM 128
#define EDGE_DIM 64
#define HID 128

typedef __attribute__((ext_vector_type(8))) short bf16x8;
typedef __attribute__((ext_vector_type(4))) float f32x4;

__device__ __forceinline__ ushort f2bf(float f) {
    unsigned int x = __float_as_uint(f);
    x += 0x7fffu + ((x >> 16) & 1u);
    return (ushort)(x >> 16);
}
__device__ __forceinline__ float bf2f(ushort u) {
    return __uint_as_float(((unsigned int)u) << 16);
}
// tanh(x) = 1 - 2/(e^{2x}+1); e^{2x}=inf -> 1, e^{2x}=0 -> -1 (no NaN)
__device__ __forceinline__ float tanh_fast(float x) {
    return 1.f - __fdividef(2.f, __expf(2.f * x) + 1.f);
}

// ---------------------------------------------------------------------------
// Launch A (256 thr): blocks 0..32 = wcomb ; blocks 33..2532 = hist
// ---------------------------------------------------------------------------
__global__ __launch_bounds__(256) void k_A(
    const float* __restrict__ W_edge, const float* __restrict__ W1,
    const float* __restrict__ b_att1, const float* __restrict__ b_edge,
    float* __restrict__ Wc, float* __restrict__ b_eff,
    const int* __restrict__ srcI, int* __restrict__ cnt)
{
    const int bid = blockIdx.x;
    if (bid < 33) {
        const float* W1he = W1 + 256 * 128;
        if (bid == 32) {
            const int n = threadIdx.x;
            if (n < 128) {
                float s = b_att1[n];
                for (int k = 0; k < 128; ++k) s = fmaf(b_edge[k], W1he[k * 128 + n], s);
                b_eff[n] = s;
            }
            return;
        }
        const int idx = bid * 256 + threadIdx.x;
        const int row = idx >> 7, n = idx & 127;
        float s = 0.f;
        for (int k = 0; k < 128; ++k) s = fmaf(W_edge[row * 128 + k], W1he[k * 128 + n], s);
        Wc[idx] = s;
    } else {
        const int e = (bid - 33) * 256 + threadIdx.x;
        atomicAdd(&cnt[srcI[e]], 1);
    }
}

// ---------------------------------------------------------------------------
// Launch B (1024 thr): blocks 0..71 = pack ; block 72 = scan
// ---------------------------------------------------------------------------
__global__ __launch_bounds__(1024) void k_B(
    const float* __restrict__ W1, const float* __restrict__ Wc,
    const float* __restrict__ Wn, const float* __restrict__ Wo,
    ushort* __restrict__ packB, ushort* __restrict__ packA,
    ushort* __restrict__ packN, ushort* __restrict__ packO,
    const int* __restrict__ cnt, int* __restrict__ rowptr)
{
    const int bid = blockIdx.x;
    if (bid < 72) {
        const int idx = bid * 1024 + threadIdx.x;   // 0..73727
        if (idx < 32768) {
            const int j = idx & 7, lane = (idx >> 3) & 63, nt = (idx >> 9) & 7, k0 = idx >> 12;
            const int k = k0 * 32 + (lane >> 4) * 8 + j;
            const int n = nt * 16 + (lane & 15);
            packB[idx] = f2bf(W1[k * 128 + n]);
        } else if (idx < 40960) {
            const int i2 = idx - 32768;
            const int j = i2 & 7, lane = (i2 >> 3) & 63, mt = (i2 >> 9) & 7, k0 = i2 >> 12;
            const int k = k0 * 32 + (lane >> 4) * 8 + j;
            const int row = mt * 16 + (lane & 15);
            packA[i2] = f2bf(Wc[k * 128 + row]);
        } else if (idx < 57344) {
            const int i3 = idx - 40960;
            const int j = i3 & 7, lane = (i3 >> 3) & 63, nt = (i3 >> 9) & 7, k0 = i3 >> 12;
            const int k = k0 * 32 + (lane >> 4) * 8 + j;
            const int n = nt * 16 + (lane & 15);
            packN[i3] = f2bf(Wn[k * 128 + n]);
        } else {
            const int i4 = idx - 57344;
            const int j = i4 & 7, lane = (i4 >> 3) & 63, nt = (i4 >> 9) & 7, k0 = i4 >> 12;
            const int k = k0 * 32 + (lane >> 4) * 8 + j;
            const int n = nt * 16 + (lane & 15);
            packO[i4] = f2bf(Wo[k * 128 + n]);
        }
        return;
    }
    // --- scan (single block, 4 elems/thread) ---
    __shared__ int wsum[16];
    __shared__ int carry;
    const int tid = threadIdx.x, lane = tid & 63, wid = tid >> 6;
    if (tid == 0) { carry = 0; rowptr[0] = 0; }
    __syncthreads();
    for (int base = 0; base < N_NODES; base += 4096) {
        const int i = base + tid * 4;
        int4 c = {0, 0, 0, 0};
        if (i < N_NODES) c = *reinterpret_cast<const int4*>(cnt + i);
        const int tsum = c.x + c.y + c.z + c.w;
        int v = tsum;
#pragma unroll
        for (int d = 1; d < 64; d <<= 1) {
            const int t = __shfl_up(v, d, 64);
            if (lane >= d) v += t;
        }
        if (lane == 63) wsum[wid] = v;
        __syncthreads();
        if (wid == 0 && lane < 16) {
            int w = wsum[lane];
#pragma unroll
            for (int d = 1; d < 16; d <<= 1) {
                const int t = __shfl_up(w, d, 16);
                if ((lane & 15) >= d) w += t;
            }
            wsum[lane] = w;
        }
        __syncthreads();
        const int off = (wid == 0) ? 0 : wsum[wid - 1];
        const int excl = carry + off + v - tsum;
        if (i < N_NODES) {
            rowptr[i + 1] = excl + c.x;
            rowptr[i + 2] = excl + c.x + c.y;
            rowptr[i + 3] = excl + c.x + c.y + c.z;
            rowptr[i + 4] = excl + tsum;
        }
        const int total = wsum[15];
        __syncthreads();
        if (tid == 0) carry += total;
        __syncthreads();
    }
}

// ---------------------------------------------------------------------------
// Launch C (256 thr): blocks 0..624 = node_hg3 ; blocks 625..3124 = fill.
// node_hg3: h = X@Wn + b (MFMA) kept ONLY in per-wave LDS tile; then three
// GEMMs off the LDS A-frags: G1 = h@W1a + b_eff (permuted store),
// G2 = h@W1b (permuted store), G3 = h@W_out (row-major store, gathered by
// k_agg; out-GEMM commuted past the weighted mean). Hb is dead.
// ---------------------------------------------------------------------------
__global__ __launch_bounds__(256) void k_C(
    const float* __restrict__ X, const ushort* __restrict__ packN,
    const ushort* __restrict__ packB, const ushort* __restrict__ packO,
    const float* __restrict__ b, const float* __restrict__ b_eff,
    ushort* __restrict__ G1, ushort* __restrict__ G2, ushort* __restrict__ G3,
    const int* __restrict__ srcI, const int* __restrict__ dstI,
    const int* __restrict__ rowptr, int* __restrict__ cursor,
    int2* __restrict__ edrec)
{
    const int bid = blockIdx.x;
    if (bid >= 625) {
        // --- fill: edrec[pos] = (e, si<<16|di), single 8B scattered store ---
        const int e = (bid - 625) * 256 + threadIdx.x;
        const int s = srcI[e];
        const int pos = rowptr[s] + atomicAdd(&cursor[s], 1);
        int2 rec;
        rec.x = e;
        rec.y = (s << 16) | dstI[e];
        edrec[pos] = rec;
        return;
    }
    // --- node_hg3 ---
    __shared__ ushort hs[4][16][144];   // 18 KB
    const int tid = threadIdx.x;
    const int wave = tid >> 6, lane = tid & 63;
    const int r = lane & 15, g = lane >> 4;
    const int nbase = bid * 64 + wave * 16;
    const float* rowX = X + (size_t)(nbase + r) * 128 + g * 8;
    const bf16x8* BpN = reinterpret_cast<const bf16x8*>(packN);
    const bf16x8* BpB = reinterpret_cast<const bf16x8*>(packB);
    const bf16x8* BpO = reinterpret_cast<const bf16x8*>(packO);

    // phase 1: h = X @ W_node + b  -> LDS only
    f32x4 acc[8];
#pragma unroll
    for (int nt = 0; nt < 8; ++nt) {
        const float bv = b[nt * 16 + r];
        acc[nt] = (f32x4){bv, bv, bv, bv};
    }
#pragma unroll
    for (int k0 = 0; k0 < 4; ++k0) {
        const float4 u0 = *reinterpret_cast<const float4*>(rowX + k0 * 32);
        const float4 u1 = *reinterpret_cast<const float4*>(rowX + k0 * 32 + 4);
        bf16x8 a;
        a[0] = (short)f2bf(u0.x); a[1] = (short)f2bf(u0.y);
        a[2] = (short)f2bf(u0.z); a[3] = (short)f2bf(u0.w);
        a[4] = (short)f2bf(u1.x); a[5] = (short)f2bf(u1.y);
        a[6] = (short)f2bf(u1.z); a[7] = (short)f2bf(u1.w);
#pragma unroll
        for (int nt = 0; nt < 8; ++nt)
            acc[nt] = __builtin_amdgcn_mfma_f32_16x16x32_bf16(
                a, BpN[(k0 * 8 + nt) * 64 + lane], acc[nt], 0, 0, 0);
    }
#pragma unroll
    for (int nt = 0; nt < 8; ++nt) {
#pragma unroll
        for (int q = 0; q < 4; ++q)
            hs[wave][g * 4 + q][nt * 16 + r] = f2bf(acc[nt][q]);
    }

    // phase 2: A-frags from LDS (same wave; lgkmcnt orders)
    bf16x8 afr[4];
#pragma unroll
    for (int k0 = 0; k0 < 4; ++k0)
        afr[k0] = *reinterpret_cast<const bf16x8*>(&hs[wave][r][k0 * 32 + g * 8]);

    const int coff = (r >> 2) * 32 + (r & 3);

    // G1 = h @ W1a + b_eff (permuted store)
#pragma unroll
    for (int nt = 0; nt < 8; ++nt) acc[nt] = (f32x4){0.f, 0.f, 0.f, 0.f};
#pragma unroll
    for (int k0 = 0; k0 < 4; ++k0) {
#pragma unroll
        for (int nt = 0; nt < 8; ++nt)
            acc[nt] = __builtin_amdgcn_mfma_f32_16x16x32_bf16(
                afr[k0], BpB[(k0 * 8 + nt) * 64 + lane], acc[nt], 0, 0, 0);
    }
#pragma unroll
    for (int nt = 0; nt < 8; ++nt) {
        const float bv = b_eff[nt * 16 + r];
#pragma unroll
        for (int q = 0; q < 4; ++q)
            G1[(size_t)(nbase + g * 4 + q) * 128 + coff + nt * 4] = f2bf(acc[nt][q] + bv);
    }

    // G2 = h @ W1b (permuted store)
#pragma unroll
    for (int nt = 0; nt < 8; ++nt) acc[nt] = (f32x4){0.f, 0.f, 0.f, 0.f};
#pragma unroll
    for (int k0 = 0; k0 < 4; ++k0) {
#pragma unroll
        for (int nt = 0; nt < 8; ++nt)
            acc[nt] = __builtin_amdgcn_mfma_f32_16x16x32_bf16(
                afr[k0], BpB[((k0 + 4) * 8 + nt) * 64 + lane], acc[nt], 0, 0, 0);
    }
#pragma unroll
    for (int nt = 0; nt < 8; ++nt) {
#pragma unroll
        for (int q = 0; q < 4; ++q)
            G2[(size_t)(nbase + g * 4 + q) * 128 + coff + nt * 4] = f2bf(acc[nt][q]);
    }

    // G3 = h @ W_out (row-major store; gathered by k_agg)
#pragma unroll
    for (int nt = 0; nt < 8; ++nt) acc[nt] = (f32x4){0.f, 0.f, 0.f, 0.f};
#pragma unroll
    for (int k0 = 0; k0 < 4; ++k0) {
#pragma unroll
        for (int nt = 0; nt < 8; ++nt)
            acc[nt] = __builtin_amdgcn_mfma_f32_16x16x32_bf16(
                afr[k0], BpO[(k0 * 8 + nt) * 64 + lane], acc[nt], 0, 0, 0);
    }
#pragma unroll
    for (int nt = 0; nt < 8; ++nt) {
#pragma unroll
        for (int q = 0; q < 4; ++q)
            G3[(size_t)(nbase + g * 4 + q) * 128 + nt * 16 + r] = f2bf(acc[nt][q]);
    }
}

// ---------------------------------------------------------------------------
// K2 v10: CSR-ordered edge attention. G1 (L1-hot) in acc init; G2 (random)
// hoisted raw, folded at tanh epilogue.
// ---------------------------------------------------------------------------
__global__ __launch_bounds__(256) void k_edge_att_v10(
    const int2* __restrict__ edrec, const float* __restrict__ EF,
    const ushort* __restrict__ G1, const ushort* __restrict__ G2,
    const ushort* __restrict__ packA,
    const float* __restrict__ W2, const float* __restrict__ b2,
    float* __restrict__ csr_p)
{
    const int tid = threadIdx.x;
    const int wave = tid >> 6, lane = tid & 63;
    const int r = lane & 15, g = lane >> 4;
    const int pbase = blockIdx.x * 64 + wave * 16;
    const int pos = pbase + r;
    const int2 rec = edrec[pos];
    const int e = rec.x;
    const int di = rec.y & 0xffff;
    const int si = ((unsigned)rec.y) >> 16;

    const ushort* g2base = G2 + (size_t)di * 128 + g * 32;
    bf16x8 g2r[4];
#pragma unroll
    for (int m2 = 0; m2 < 4; ++m2)
        g2r[m2] = *reinterpret_cast<const bf16x8*>(g2base + m2 * 8);

    const ushort* g1base = G1 + (size_t)si * 128 + g * 32;
    f32x4 acc[8];
#pragma unroll
    for (int m2 = 0; m2 < 4; ++m2) {
        const bf16x8 a = *reinterpret_cast<const bf16x8*>(g1base + m2 * 8);
#pragma unroll
        for (int q = 0; q < 4; ++q) {
            acc[2 * m2][q]     = bf2f((ushort)a[q]);
            acc[2 * m2 + 1][q] = bf2f((ushort)a[4 + q]);
        }
    }

    const float* rowE = EF + (size_t)e * 64 + g * 8;
    bf16x8 b0, b1;
    {
        const float4 u0 = *reinterpret_cast<const float4*>(rowE);
        const float4 u1 = *reinterpret_cast<const float4*>(rowE + 4);
        b0[0] = (short)f2bf(u0.x); b0[1] = (short)f2bf(u0.y);
        b0[2] = (short)f2bf(u0.z); b0[3] = (short)f2bf(u0.w);
        b0[4] = (short)f2bf(u1.x); b0[5] = (short)f2bf(u1.y);
        b0[6] = (short)f2bf(u1.z); b0[7] = (short)f2bf(u1.w);
        const float4 v0 = *reinterpret_cast<const float4*>(rowE + 32);
        const float4 v1 = *reinterpret_cast<const float4*>(rowE + 36);
        b1[0] = (short)f2bf(v0.x); b1[1] = (short)f2bf(v0.y);
        b1[2] = (short)f2bf(v0.z); b1[3] = (short)f2bf(v0.w);
        b1[4] = (short)f2bf(v1.x); b1[5] = (short)f2bf(v1.y);
        b1[6] = (short)f2bf(v1.z); b1[7] = (short)f2bf(v1.w);
    }

    const bf16x8* Ap = reinterpret_cast<const bf16x8*>(packA);
#pragma unroll
    for (int mt = 0; mt < 8; ++mt)
        acc[mt] = __builtin_amdgcn_mfma_f32_16x16x32_bf16(
            Ap[(0 * 8 + mt) * 64 + lane], b0, acc[mt], 0, 0, 0);
#pragma unroll
    for (int mt = 0; mt < 8; ++mt)
        acc[mt] = __builtin_amdgcn_mfma_f32_16x16x32_bf16(
            Ap[(1 * 8 + mt) * 64 + lane], b1, acc[mt], 0, 0, 0);

    float part = 0.f;
#pragma unroll
    for (int mt = 0; mt < 8; ++mt) {
        const bf16x8 gr = g2r[mt >> 1];
        const int h4 = (mt & 1) * 4;
        const float4 w2v = *reinterpret_cast<const float4*>(W2 + mt * 16 + g * 4);
        const float z0 = acc[mt][0] + bf2f((ushort)gr[h4 + 0]);
        const float z1 = acc[mt][1] + bf2f((ushort)gr[h4 + 1]);
        const float z2 = acc[mt][2] + bf2f((ushort)gr[h4 + 2]);
        const float z3 = acc[mt][3] + bf2f((ushort)gr[h4 + 3]);
        part = fmaf(tanh_fast(z0), w2v.x, part);
        part = fmaf(tanh_fast(z1), w2v.y, part);
        part = fmaf(tanh_fast(z2), w2v.z, part);
        part = fmaf(tanh_fast(z3), w2v.w, part);
    }
    part += __shfl_xor(part, 16, 64);
    part += __shfl_xor(part, 32, 64);
    if (lane < 16) csr_p[pos] = __expf(part + b2[0]);
}

// ---------------------------------------------------------------------------
// K3: per-node gather-aggregate over G3 + fused bias + LayerNorm + ReLU.
// wave-per-node; 4 edge-slots x 16 col-lanes; x2 unrolled. After the
// slot-butterfly ALL lanes hold the full row totals, so LN reduces with
// masks 1..8 (within 16-lane groups) and lanes<16 store fp32 OUT directly.
// ---------------------------------------------------------------------------
__global__ __launch_bounds__(256) void k_agg(
    const int* __restrict__ rowptr, const float* __restrict__ csr_p,
    const int2* __restrict__ edrec, const ushort* __restrict__ G3,
    const float* __restrict__ b_out, const float* __restrict__ gamma,
    const float* __restrict__ beta, float* __restrict__ OUT)
{
    const int tid = threadIdx.x;
    const int wave = tid >> 6, lane = tid & 63;
    const int slot = lane >> 4, tc = lane & 15;
    const int n = blockIdx.x * 4 + wave;
    const int beg = rowptr[n], end = rowptr[n + 1];

    float v[8];
#pragma unroll
    for (int i = 0; i < 8; ++i) v[i] = 0.f;
    float sp = 0.f;

    int j = beg + slot;
    for (; j + 4 < end; j += 8) {
        const float p0 = csr_p[j];
        const int d0 = edrec[j].y & 0xffff;
        const float p1 = csr_p[j + 4];
        const int d1 = edrec[j + 4].y & 0xffff;
        const bf16x8 h0 = *reinterpret_cast<const bf16x8*>(G3 + (size_t)d0 * 128 + tc * 8);
        const bf16x8 h1 = *reinterpret_cast<const bf16x8*>(G3 + (size_t)d1 * 128 + tc * 8);
#pragma unroll
        for (int i = 0; i < 8; ++i) {
            v[i] = fmaf(p0, bf2f((ushort)h0[i]), v[i]);
            v[i] = fmaf(p1, bf2f((ushort)h1[i]), v[i]);
        }
        sp += p0 + p1;
    }
    for (; j < end; j += 4) {
        const float p = csr_p[j];
        const int d = edrec[j].y & 0xffff;
        const bf16x8 hv = *reinterpret_cast<const bf16x8*>(G3 + (size_t)d * 128 + tc * 8);
#pragma unroll
        for (int i = 0; i < 8; ++i) v[i] = fmaf(p, bf2f((ushort)hv[i]), v[i]);
        sp += p;
    }
    // slot butterfly: afterwards every lane holds the full totals for col tc
#pragma unroll
    for (int m = 16; m <= 32; m <<= 1) {
#pragma unroll
        for (int i = 0; i < 8; ++i) v[i] += __shfl_xor(v[i], m, 64);
        sp += __shfl_xor(sp, m, 64);
    }

    // x = agg + b_out ; LayerNorm over 128 cols (in-lane 8 + 16-lane butterfly)
    const float inv = (end > beg) ? 1.f / sp : 0.f;
    const float4 bo0 = *reinterpret_cast<const float4*>(b_out + tc * 8);
    const float4 bo1 = *reinterpret_cast<const float4*>(b_out + tc * 8 + 4);
    float x[8];
    x[0] = fmaf(v[0], inv, bo0.x); x[1] = fmaf(v[1], inv, bo0.y);
    x[2] = fmaf(v[2], inv, bo0.z); x[3] = fmaf(v[3], inv, bo0.w);
    x[4] = fmaf(v[4], inv, bo1.x); x[5] = fmaf(v[5], inv, bo1.y);
    x[6] = fmaf(v[6], inv, bo1.z); x[7] = fmaf(v[7], inv, bo1.w);

    float s1 = 0.f, s2 = 0.f;
#pragma unroll
    for (int i = 0; i < 8; ++i) { s1 += x[i]; s2 = fmaf(x[i], x[i], s2); }
#pragma unroll
    for (int m = 1; m <= 8; m <<= 1) {
        s1 += __shfl_xor(s1, m, 64);
        s2 += __shfl_xor(s2, m, 64);
    }
    const float mu = s1 * (1.f / 128.f);
    const float var = s2 * (1.f / 128.f) - mu * mu;
    const float rr = rsqrtf(var + 1e-5f);

    if (lane < 16) {
        const float4 ga0 = *reinterpret_cast<const float4*>(gamma + tc * 8);
        const float4 ga1 = *reinterpret_cast<const float4*>(gamma + tc * 8 + 4);
        const float4 be0 = *reinterpret_cast<const float4*>(beta + tc * 8);
        const float4 be1 = *reinterpret_cast<const float4*>(beta + tc * 8 + 4);
        float4 o0, o1;
        o0.x = (x[0] - mu) * rr * ga0.x + be0.x;
        o0.y = (x[1] - mu) * rr * ga0.y + be0.y;
        o0.z = (x[2] - mu) * rr * ga0.z + be0.z;
        o0.w = (x[3] - mu) * rr * ga0.w + be0.w;
        o1.x = (x[4] - mu) * rr * ga1.x + be1.x;
        o1.y = (x[5] - mu) * rr * ga1.y + be1.y;
        o1.z = (x[6] - mu) * rr * ga1.z + be1.z;
        o1.w = (x[7] - mu) * rr * ga1.w + be1.w;
        o0.x = o0.x > 0.f ? o0.x : 0.f; o0.y = o0.y > 0.f ? o0.y : 0.f;
        o0.z = o0.z > 0.f ? o0.z : 0.f; o0.w = o0.w > 0.f ? o0.w : 0.f;
        o1.x = o1.x > 0.f ? o1.x : 0.f; o1.y = o1.y > 0.f ? o1.y : 0.f;
        o1.z = o1.z > 0.f ? o1.z : 0.f; o1.w = o1.w > 0.f ? o1.w : 0.f;
        float* orow = OUT + (size_t)n * 128 + tc * 8;
        *reinterpret_cast<float4*>(orow) = o0;
        *reinterpret_cast<float4*>(orow + 4) = o1;
    }
}

// ---------------------------------------------------------------------------
extern "C" void kernel_launch(void* const* d_in, const int* in_sizes, int n_in,
                              void* d_out, int out_size, void* d_ws, size_t ws_size,
                              hipStream_t stream)
{
    const float* node_features = (const float*)d_in[0];
    const int*   edge_index    = (const int*)d_in[1];
    const float* edge_features = (const float*)d_in[2];
    const float* W_node  = (const float*)d_in[3];
    const float* b_node  = (const float*)d_in[4];
    const float* W_edge  = (const float*)d_in[5];
    const float* b_edge  = (const float*)d_in[6];
    const float* W_att1  = (const float*)d_in[7];
    const float* b_att1  = (const float*)d_in[8];
    const float* W_att2  = (const float*)d_in[9];
    const float* b_att2  = (const float*)d_in[10];
    const float* W_out   = (const float*)d_in[11];
    const float* b_out   = (const float*)d_in[12];
    const float* ln_gamma = (const float*)d_in[13];
    const float* ln_beta  = (const float*)d_in[14];
    float* out = (float*)d_out;

    // workspace layout (byte offsets, 16B-aligned)
    char* ws = (char*)d_ws;
    ushort* G3      = (ushort*)(ws);                   // 10,240,000 B
    ushort* G1      = (ushort*)(ws + 10240000);        // 10,240,000 B
    ushort* G2      = (ushort*)(ws + 20480000);        // 10,240,000 B
    float*  csr_p   = (float*)(ws + 40960000);         //  2,560,000 B
    int2*   edrec   = (int2*)(ws + 43520000);          //  5,120,000 B
    int*    rowptr  = (int*)(ws + 48640000);           //    160,004 B
    int*    cnt     = (int*)(ws + 48800016);           //    160,000 B
    int*    cursor  = (int*)(ws + 48960016);           //    160,000 B (contiguous after cnt)
    float*  Wc      = (float*)(ws + 49120016);         //     32,768 B
    float*  b_eff   = (float*)(ws + 49152784);         //        512 B
    ushort* packB   = (ushort*)(ws + 49153296);        //     65,536 B
    ushort* packA   = (ushort*)(ws + 49218832);        //     16,384 B
    ushort* packN   = (ushort*)(ws + 49235216);        //     32,768 B
    ushort* packO   = (ushort*)(ws + 49267984);        //     32,768 B

    const int* srcI = edge_index;
    const int* dstI = edge_index + N_EDGES;

    // zero histogram + fill cursors (contiguous)
    hipMemsetAsync(cnt, 0, 320000, stream);

    // A: wcomb (33) + hist (2500)
    k_A<<<2533, 256, 0, stream>>>(W_edge, W_att1, b_att1, b_edge, Wc, b_eff,
                                  srcI, cnt);
    // B: pack (72x1024) + scan (1)
    k_B<<<73, 1024, 0, stream>>>(W_att1, Wc, W_node, W_out,
                                 packB, packA, packN, packO, cnt, rowptr);
    // C: node_hg3 (625: node_gemm + G1/G2/G3 fused) + fill (2500)
    k_C<<<3125, 256, 0, stream>>>(node_features, packN, packB, packO,
                                  b_node, b_eff, G1, G2, G3,
                                  srcI, dstI, rowptr, cursor, edrec);
    k_edge_att_v10<<<N_EDGES / 64, 256, 0, stream>>>(edrec, edge_features,
                                                     G1, G2, packA, W_att2, b_att2,
                                                     csr_p);
    k_agg<<<N_NODES / 4, 256, 0, stream>>>(rowptr, csr_p, edrec, G3,
                                           b_out, ln_gamma, ln_beta, out);
}